// Round 19
// baseline (69.760 us; speedup 1.0000x reference)
//
#include <hip/hip_runtime.h>
#include <hip/hip_bf16.h>
#include <stdint.h>

// out_re[b,i] = sum_{j,l} Re{ x[b,j,l]*k[i,j]*conj(k[i,l]) },  d_out = Re only.
//   T_re = P·R + Q·M ; T_im = P·M + Q·(-R)  (A = K-frags in regs, B = X in LDS)
//   out_re[b,i] = sum_j T_re*p[i,j] - T_im*q[i,j]
// Round-19: TWO blocks per CU (the one untested lever; r16's attempt spilled).
// Keep r18's 512-thr dual-stream wave layout (VGPR=128, spill-free x3 rounds);
// shrink to 2 bufs/stream -> LDS 64.5KB -> 2 resident barrier groups per CU:
// block B issues through block A's WAITV/barrier bubbles. Depth-2 is latency-
// sufficient (stage has a full ~3200cyc phase to land >> 900cyc HBM). NBAT=4,
// grid=512. vmcnt FIFO re-derived incl. stores: steady WAITV(4), tail 4/0;
// WAR covered by the second barrier (barrier count proven free in r18).

typedef __attribute__((ext_vector_type(8))) __bf16 bf16x8;
typedef __attribute__((ext_vector_type(4))) float f32x4;
typedef __attribute__((ext_vector_type(4))) unsigned int u32x4;

#define EDIM 128
#define NBAT 4
#define XBUF 16384
#define SSTR (2 * XBUF)          // stream stride (2 bufs of 16KB)
#define PART_OFF (2 * SSTR)      // 65536
#define LDS_BYTES (2 * SSTR + 512)

static __device__ inline bf16x8 neg8(bf16x8 v) {
    u32x4 u = __builtin_bit_cast(u32x4, v);
    u ^= (u32x4){0x80008000u, 0x80008000u, 0x80008000u, 0x80008000u};
    return __builtin_bit_cast(bf16x8, u);
}

#define ASG(p) (__attribute__((address_space(1))) const void*)(p)
#define ASL(p) (__attribute__((address_space(3))) void*)(p)
#define WAITV(N_) asm volatile("s_waitcnt vmcnt(" #N_ ")" ::: "memory")
#define WAITLGKM() asm volatile("s_waitcnt lgkmcnt(0)" ::: "memory")
#define BARRIER() asm volatile("s_barrier" ::: "memory")

__global__ __launch_bounds__(512, 2) void qmeas_kernel(
    const float* __restrict__ R, const float* __restrict__ M,
    const float* __restrict__ Kern, float* __restrict__ out, int nout)
{
    extern __shared__ unsigned char smem[];  // stream0 32K | stream1 32K | part

    const int t    = threadIdx.x;
    const int lane = t & 63;
    const int w    = t >> 6;       // wave 0..7
    const int li   = lane & 15;
    const int s    = lane >> 4;    // 0..3
    const int rhi  = lane >> 5;    // 0..1
    const int iw   = w & 3;        // i-block [32iw, 32iw+32)
    const int jh   = w >> 2;       // j-half (chunk stream)
    const int key  = li & 7;
    const int bat0 = blockIdx.x * NBAT;

    // ---- K-A fragments in regs (64 VGPR), loaded once ----
    bf16x8 pa[2][4], qa[2][4];
#pragma unroll
    for (int nn = 0; nn < 2; ++nn) {
#pragma unroll
        for (int u = 0; u < 4; ++u) {
            const int i = (iw * 2 + nn) * 16 + li;
            const float* g = Kern + (((size_t)i * EDIM + u * 32 + s * 8) << 1);
            f32x4 f0 = *(const f32x4*)(g);
            f32x4 f1 = *(const f32x4*)(g + 4);
            f32x4 f2 = *(const f32x4*)(g + 8);
            f32x4 f3 = *(const f32x4*)(g + 12);
            bf16x8 pv, qv;
            pv[0] = (__bf16)f0[0]; qv[0] = (__bf16)f0[1];
            pv[1] = (__bf16)f0[2]; qv[1] = (__bf16)f0[3];
            pv[2] = (__bf16)f1[0]; qv[2] = (__bf16)f1[1];
            pv[3] = (__bf16)f1[2]; qv[3] = (__bf16)f1[3];
            pv[4] = (__bf16)f2[0]; qv[4] = (__bf16)f2[1];
            pv[5] = (__bf16)f2[2]; qv[5] = (__bf16)f2[3];
            pv[6] = (__bf16)f3[0]; qv[6] = (__bf16)f3[1];
            pv[7] = (__bf16)f3[2]; qv[7] = (__bf16)f3[3];
            pa[nn][u] = pv;
            qa[nn][u] = qv;
        }
    }

    // ---- epilogue weights (32 VGPR): kwp[nn][p] at
    //      k[(2iw+nn)*16 + s*4 + r][(jh*4+p)*16 + li] ----
    const float2* K2 = (const float2*)Kern;
    bf16x8 kwp[2][4];
#pragma unroll
    for (int nn = 0; nn < 2; ++nn) {
#pragma unroll
        for (int p = 0; p < 4; ++p) {
#pragma unroll
            for (int r = 0; r < 4; ++r) {
                float2 kv = K2[(size_t)((iw * 2 + nn) * 16 + s * 4 + r) * EDIM
                               + (jh * 4 + p) * 16 + li];
                kwp[nn][p][2 * r]     = (__bf16)kv.x;
                kwp[nn][p][2 * r + 1] = (__bf16)kv.y;
            }
        }
    }

    // stage phase p_ chunks for BOTH streams into buf o_ (4 DMA/thread)
#define STAGE2(xb_, p_, o_)                                                     \
    do {                                                                        \
        _Pragma("unroll")                                                       \
        for (int st = 0; st < 2; ++st) {                                        \
            const int c_   = st * 4 + (p_);                                     \
            const int sb_  = st * SSTR + (o_);                                  \
            const int rowl = (w << 1) + rhi;                                    \
            const int colf = (((lane & 31) ^ (rowl & 7)) << 2);                 \
            const size_t src = (xb_) + (size_t)(c_ * 16 + rowl) * EDIM + colf;  \
            unsigned char* dR = smem + sb_ + w * 1024;                          \
            __builtin_amdgcn_global_load_lds(ASG(R + src), ASL(dR), 16, 0, 0);  \
            __builtin_amdgcn_global_load_lds(ASG(M + src), ASL(dR + 8192), 16, 0, 0); \
        }                                                                       \
    } while (0)

    // prologue: quarters 0,1 into bufs 0,1 (both streams)
    const size_t xb0 = (size_t)bat0 * (EDIM * EDIM);
    STAGE2(xb0, 0, 0 * XBUF);
    STAGE2(xb0, 1, 1 * XBUF);

    float reS[2][4] = {{0.f,0.f,0.f,0.f},{0.f,0.f,0.f,0.f}};
    float* part = (float*)(smem + PART_OFF);

    // compute this wave's chunk of phase p_ from its stream's buf o_
#define COMPUTE_FOLD(p_, o_)                                                    \
    do {                                                                        \
        const unsigned char* Xb = smem + (jh ? SSTR : 0) + (o_);                \
        f32x4 are0 = (f32x4){0.f,0.f,0.f,0.f}, are1 = (f32x4){0.f,0.f,0.f,0.f}; \
        f32x4 aim0 = (f32x4){0.f,0.f,0.f,0.f}, aim1 = (f32x4){0.f,0.f,0.f,0.f}; \
        _Pragma("unroll")                                                       \
        for (int u = 0; u < 4; ++u) {                                           \
            int c0 = (u << 3) + (s << 1);                                       \
            int a0 = li * 512 + ((c0 ^ key) << 4);                              \
            int a1 = li * 512 + (((c0 + 1) ^ key) << 4);                        \
            f32x4 r0 = *(const f32x4*)(Xb + a0);                                \
            f32x4 r1 = *(const f32x4*)(Xb + a1);                                \
            f32x4 m0 = *(const f32x4*)(Xb + 8192 + a0);                         \
            f32x4 m1 = *(const f32x4*)(Xb + 8192 + a1);                         \
            bf16x8 xr, xm;                                                      \
            _Pragma("unroll")                                                   \
            for (int e = 0; e < 4; ++e) {                                       \
                xr[e] = (__bf16)r0[e]; xr[4 + e] = (__bf16)r1[e];               \
                xm[e] = (__bf16)m0[e]; xm[4 + e] = (__bf16)m1[e];               \
            }                                                                   \
            bf16x8 xrn = neg8(xr);                                              \
            are0 = __builtin_amdgcn_mfma_f32_16x16x32_bf16(pa[0][u], xr,  are0, 0, 0, 0); \
            are0 = __builtin_amdgcn_mfma_f32_16x16x32_bf16(qa[0][u], xm,  are0, 0, 0, 0); \
            aim0 = __builtin_amdgcn_mfma_f32_16x16x32_bf16(pa[0][u], xm,  aim0, 0, 0, 0); \
            aim0 = __builtin_amdgcn_mfma_f32_16x16x32_bf16(qa[0][u], xrn, aim0, 0, 0, 0); \
            are1 = __builtin_amdgcn_mfma_f32_16x16x32_bf16(pa[1][u], xr,  are1, 0, 0, 0); \
            are1 = __builtin_amdgcn_mfma_f32_16x16x32_bf16(qa[1][u], xm,  are1, 0, 0, 0); \
            aim1 = __builtin_amdgcn_mfma_f32_16x16x32_bf16(pa[1][u], xm,  aim1, 0, 0, 0); \
            aim1 = __builtin_amdgcn_mfma_f32_16x16x32_bf16(qa[1][u], xrn, aim1, 0, 0, 0); \
        }                                                                       \
        {                                                                       \
            const bf16x8 kv0 = kwp[0][p_];                                      \
            const bf16x8 kv1 = kwp[1][p_];                                      \
            _Pragma("unroll")                                                   \
            for (int r = 0; r < 4; ++r) {                                       \
                reS[0][r] += are0[r] * (float)kv0[2*r] - aim0[r] * (float)kv0[2*r+1]; \
                reS[1][r] += are1[r] * (float)kv1[2*r] - aim1[r] * (float)kv1[2*r+1]; \
            }                                                                   \
        }                                                                       \
    } while (0)

#pragma unroll 1
    for (int n = 0; n < NBAT; ++n) {
        const size_t xbn  = (size_t)(bat0 + n) * (EDIM * EDIM);
        const size_t xbn1 = xbn + (size_t)(EDIM * EDIM);
        const bool more = (n + 1 < NBAT);

        // p0: compute buf0 (q0); stage q2 -> buf0
        WAITV(4); BARRIER();
        COMPUTE_FOLD(0, 0 * XBUF);
        BARRIER();
        STAGE2(xbn, 2, 0 * XBUF);

        // p1: compute buf1 (q1); stage q3 -> buf1
        WAITV(4); BARRIER();
        COMPUTE_FOLD(1, 1 * XBUF);
        BARRIER();
        STAGE2(xbn, 3, 1 * XBUF);

        // p2: compute buf0 (q2); stage (n+1,q0) -> buf0
        WAITV(4); BARRIER();
        COMPUTE_FOLD(2, 0 * XBUF);
        BARRIER();
        if (more) STAGE2(xbn1, 0, 0 * XBUF);

        // p3: compute buf1 (q3); combine + store; stage (n+1,q1) -> buf1
        if (more) { WAITV(4); } else { WAITV(0); }
        BARRIER();
        COMPUTE_FOLD(3, 1 * XBUF);
#pragma unroll
        for (int nn = 0; nn < 2; ++nn) {
#pragma unroll
            for (int r = 0; r < 4; ++r) {
                reS[nn][r] += __shfl_xor(reS[nn][r], 1);
                reS[nn][r] += __shfl_xor(reS[nn][r], 2);
                reS[nn][r] += __shfl_xor(reS[nn][r], 4);
                reS[nn][r] += __shfl_xor(reS[nn][r], 8);
            }
        }
        if (jh == 0 && li == 0) {
#pragma unroll
            for (int nn = 0; nn < 2; ++nn) {
                f32x4 o;
                o[0] = reS[nn][0]; o[1] = reS[nn][1];
                o[2] = reS[nn][2]; o[3] = reS[nn][3];
                *(f32x4*)(part + (iw * 2 + nn) * 16 + s * 4) = o;
            }
        }
        WAITLGKM();
        BARRIER();                       // part visible to jh1 + buf1 consumed
        if (jh == 1 && li == 0) {
#pragma unroll
            for (int nn = 0; nn < 2; ++nn) {
                f32x4 pv = *(const f32x4*)(part + (iw * 2 + nn) * 16 + s * 4);
                int oi = (bat0 + n) * EDIM + (iw * 2 + nn) * 16 + s * 4;
                if (oi + 3 < nout) {
                    f32x4 o;
                    o[0] = reS[nn][0] + pv[0];
                    o[1] = reS[nn][1] + pv[1];
                    o[2] = reS[nn][2] + pv[2];
                    o[3] = reS[nn][3] + pv[3];
                    *(f32x4*)(out + oi) = o;
                }
            }
        }
        reS[0][0]=reS[0][1]=reS[0][2]=reS[0][3]=0.f;
        reS[1][0]=reS[1][1]=reS[1][2]=reS[1][3]=0.f;
        if (more) STAGE2(xbn1, 1, 1 * XBUF);
    }
}

extern "C" void kernel_launch(void* const* d_in, const int* in_sizes, int n_in,
                              void* d_out, int out_size, void* d_ws, size_t ws_size,
                              hipStream_t stream) {
    const float* R    = (const float*)d_in[0];
    const float* M    = (const float*)d_in[1];
    const float* Kern = (const float*)d_in[2];
    float*       out  = (float*)d_out;
    const int    B    = in_sizes[0] / (EDIM * EDIM);   // 2048

    hipFuncSetAttribute((const void*)qmeas_kernel,
                        hipFuncAttributeMaxDynamicSharedMemorySize, LDS_BYTES);

    int grid = B / NBAT;   // 512 -> 2 blocks/CU
    qmeas_kernel<<<grid, 512, LDS_BYTES, stream>>>(R, M, Kern, out, out_size);
}

// Round 20
// 56.073 us; speedup vs baseline: 1.2441x; 1.2441x over previous
//
#include <hip/hip_runtime.h>
#include <hip/hip_bf16.h>
#include <stdint.h>

// out_re[b,i] = sum_{j,l} Re{ x[b,j,l]*k[i,j]*conj(k[i,l]) },  d_out = Re only.
//   T_re = P·R + Q·M ; T_im = P·M + Q·(-R)  (A = K-frags in regs, B = X in LDS)
//   out_re[b,i] = sum_j T_re*p[i,j] - T_im*q[i,j]
// Round-20: r18 (best, 56.8us) + STAGE HOIST (T3 rule): issue STAGE2 right
// after the phase barrier, BEFORE compute — each stage gains a full compute
// phase of landing window (~800cyc earlier issue). vmcnt FIFO re-derived:
// outstanding at phase-p wait = stages p,p+1,p+2 = 12 ops -> steady WAITV(8)
// drains exactly stage(p); tail 8/8/4/0 unchanged. WAR: stage target buf
// (p+3)%4 == (p-1)%4 consumed before this phase's barrier. r19's 2-block/CU
// experiment regressed (69.8) and is reverted.

typedef __attribute__((ext_vector_type(8))) __bf16 bf16x8;
typedef __attribute__((ext_vector_type(4))) float f32x4;
typedef __attribute__((ext_vector_type(4))) unsigned int u32x4;

#define EDIM 128
#define NBAT 8
#define XBUF 16384
#define SSTR (4 * XBUF)          // stream stride (4 bufs of 16KB)
#define PART_OFF (2 * SSTR)      // 131072
#define LDS_BYTES (2 * SSTR + 512)

static __device__ inline bf16x8 neg8(bf16x8 v) {
    u32x4 u = __builtin_bit_cast(u32x4, v);
    u ^= (u32x4){0x80008000u, 0x80008000u, 0x80008000u, 0x80008000u};
    return __builtin_bit_cast(bf16x8, u);
}

#define ASG(p) (__attribute__((address_space(1))) const void*)(p)
#define ASL(p) (__attribute__((address_space(3))) void*)(p)
#define WAITV(N_) asm volatile("s_waitcnt vmcnt(" #N_ ")" ::: "memory")
#define WAITLGKM() asm volatile("s_waitcnt lgkmcnt(0)" ::: "memory")
#define BARRIER() asm volatile("s_barrier" ::: "memory")

__global__ __launch_bounds__(512, 2) void qmeas_kernel(
    const float* __restrict__ R, const float* __restrict__ M,
    const float* __restrict__ Kern, float* __restrict__ out, int nout)
{
    extern __shared__ unsigned char smem[];  // stream0 64K | stream1 64K | part

    const int t    = threadIdx.x;
    const int lane = t & 63;
    const int w    = t >> 6;       // wave 0..7
    const int li   = lane & 15;
    const int s    = lane >> 4;    // 0..3
    const int rhi  = lane >> 5;    // 0..1
    const int iw   = w & 3;        // i-block [32iw, 32iw+32)
    const int jh   = w >> 2;       // j-half (chunk stream)
    const int key  = li & 7;
    const int bat0 = blockIdx.x * NBAT;

    // ---- K-A fragments in regs (64 VGPR), loaded once ----
    bf16x8 pa[2][4], qa[2][4];
#pragma unroll
    for (int nn = 0; nn < 2; ++nn) {
#pragma unroll
        for (int u = 0; u < 4; ++u) {
            const int i = (iw * 2 + nn) * 16 + li;
            const float* g = Kern + (((size_t)i * EDIM + u * 32 + s * 8) << 1);
            f32x4 f0 = *(const f32x4*)(g);
            f32x4 f1 = *(const f32x4*)(g + 4);
            f32x4 f2 = *(const f32x4*)(g + 8);
            f32x4 f3 = *(const f32x4*)(g + 12);
            bf16x8 pv, qv;
            pv[0] = (__bf16)f0[0]; qv[0] = (__bf16)f0[1];
            pv[1] = (__bf16)f0[2]; qv[1] = (__bf16)f0[3];
            pv[2] = (__bf16)f1[0]; qv[2] = (__bf16)f1[1];
            pv[3] = (__bf16)f1[2]; qv[3] = (__bf16)f1[3];
            pv[4] = (__bf16)f2[0]; qv[4] = (__bf16)f2[1];
            pv[5] = (__bf16)f2[2]; qv[5] = (__bf16)f2[3];
            pv[6] = (__bf16)f3[0]; qv[6] = (__bf16)f3[1];
            pv[7] = (__bf16)f3[2]; qv[7] = (__bf16)f3[3];
            pa[nn][u] = pv;
            qa[nn][u] = qv;
        }
    }

    // ---- epilogue weights (32 VGPR): kwp[nn][p] at
    //      k[(2iw+nn)*16 + s*4 + r][(jh*4+p)*16 + li] ----
    const float2* K2 = (const float2*)Kern;
    bf16x8 kwp[2][4];
#pragma unroll
    for (int nn = 0; nn < 2; ++nn) {
#pragma unroll
        for (int p = 0; p < 4; ++p) {
#pragma unroll
            for (int r = 0; r < 4; ++r) {
                float2 kv = K2[(size_t)((iw * 2 + nn) * 16 + s * 4 + r) * EDIM
                               + (jh * 4 + p) * 16 + li];
                kwp[nn][p][2 * r]     = (__bf16)kv.x;
                kwp[nn][p][2 * r + 1] = (__bf16)kv.y;
            }
        }
    }

    // stage phase p_ chunks for BOTH streams into buf o_ (4 DMA/thread)
#define STAGE2(xb_, p_, o_)                                                     \
    do {                                                                        \
        _Pragma("unroll")                                                       \
        for (int st = 0; st < 2; ++st) {                                        \
            const int c_   = st * 4 + (p_);                                     \
            const int sb_  = st * SSTR + (o_);                                  \
            const int rowl = (w << 1) + rhi;                                    \
            const int colf = (((lane & 31) ^ (rowl & 7)) << 2);                 \
            const size_t src = (xb_) + (size_t)(c_ * 16 + rowl) * EDIM + colf;  \
            unsigned char* dR = smem + sb_ + w * 1024;                          \
            __builtin_amdgcn_global_load_lds(ASG(R + src), ASL(dR), 16, 0, 0);  \
            __builtin_amdgcn_global_load_lds(ASG(M + src), ASL(dR + 8192), 16, 0, 0); \
        }                                                                       \
    } while (0)

    // prologue: phases 0,1,2 into bufs 0,1,2 (both streams)
    const size_t xb0 = (size_t)bat0 * (EDIM * EDIM);
    STAGE2(xb0, 0, 0 * XBUF);
    STAGE2(xb0, 1, 1 * XBUF);
    STAGE2(xb0, 2, 2 * XBUF);

    float reS[2][4] = {{0.f,0.f,0.f,0.f},{0.f,0.f,0.f,0.f}};
    float* part = (float*)(smem + PART_OFF);

    // compute this wave's chunk of phase p_ from its stream's buf o_
#define COMPUTE_FOLD(p_, o_)                                                    \
    do {                                                                        \
        const unsigned char* Xb = smem + (jh ? SSTR : 0) + (o_);                \
        f32x4 are0 = (f32x4){0.f,0.f,0.f,0.f}, are1 = (f32x4){0.f,0.f,0.f,0.f}; \
        f32x4 aim0 = (f32x4){0.f,0.f,0.f,0.f}, aim1 = (f32x4){0.f,0.f,0.f,0.f}; \
        _Pragma("unroll")                                                       \
        for (int u = 0; u < 4; ++u) {                                           \
            int c0 = (u << 3) + (s << 1);                                       \
            int a0 = li * 512 + ((c0 ^ key) << 4);                              \
            int a1 = li * 512 + (((c0 + 1) ^ key) << 4);                        \
            f32x4 r0 = *(const f32x4*)(Xb + a0);                                \
            f32x4 r1 = *(const f32x4*)(Xb + a1);                                \
            f32x4 m0 = *(const f32x4*)(Xb + 8192 + a0);                         \
            f32x4 m1 = *(const f32x4*)(Xb + 8192 + a1);                         \
            bf16x8 xr, xm;                                                      \
            _Pragma("unroll")                                                   \
            for (int e = 0; e < 4; ++e) {                                       \
                xr[e] = (__bf16)r0[e]; xr[4 + e] = (__bf16)r1[e];               \
                xm[e] = (__bf16)m0[e]; xm[4 + e] = (__bf16)m1[e];               \
            }                                                                   \
            bf16x8 xrn = neg8(xr);                                              \
            are0 = __builtin_amdgcn_mfma_f32_16x16x32_bf16(pa[0][u], xr,  are0, 0, 0, 0); \
            are0 = __builtin_amdgcn_mfma_f32_16x16x32_bf16(qa[0][u], xm,  are0, 0, 0, 0); \
            aim0 = __builtin_amdgcn_mfma_f32_16x16x32_bf16(pa[0][u], xm,  aim0, 0, 0, 0); \
            aim0 = __builtin_amdgcn_mfma_f32_16x16x32_bf16(qa[0][u], xrn, aim0, 0, 0, 0); \
            are1 = __builtin_amdgcn_mfma_f32_16x16x32_bf16(pa[1][u], xr,  are1, 0, 0, 0); \
            are1 = __builtin_amdgcn_mfma_f32_16x16x32_bf16(qa[1][u], xm,  are1, 0, 0, 0); \
            aim1 = __builtin_amdgcn_mfma_f32_16x16x32_bf16(pa[1][u], xm,  aim1, 0, 0, 0); \
            aim1 = __builtin_amdgcn_mfma_f32_16x16x32_bf16(qa[1][u], xrn, aim1, 0, 0, 0); \
        }                                                                       \
        {                                                                       \
            const bf16x8 kv0 = kwp[0][p_];                                      \
            const bf16x8 kv1 = kwp[1][p_];                                      \
            _Pragma("unroll")                                                   \
            for (int r = 0; r < 4; ++r) {                                       \
                reS[0][r] += are0[r] * (float)kv0[2*r] - aim0[r] * (float)kv0[2*r+1]; \
                reS[1][r] += are1[r] * (float)kv1[2*r] - aim1[r] * (float)kv1[2*r+1]; \
            }                                                                   \
        }                                                                       \
    } while (0)

#pragma unroll 1
    for (int n = 0; n < NBAT; ++n) {
        const size_t xbn  = (size_t)(bat0 + n) * (EDIM * EDIM);
        const size_t xbn1 = xbn + (size_t)(EDIM * EDIM);
        const bool more = (n + 1 < NBAT);

        // p0: stage (n,q3)->buf3 FIRST (T3 hoist), then compute buf0
        WAITV(8); BARRIER();
        STAGE2(xbn, 3, 3 * XBUF);
        COMPUTE_FOLD(0, 0 * XBUF);

        // p1: stage (n+1,q0)->buf0, then compute buf1
        WAITV(8); BARRIER();
        if (more) STAGE2(xbn1, 0, 0 * XBUF);
        COMPUTE_FOLD(1, 1 * XBUF);

        // p2: stage (n+1,q1)->buf1, then compute buf2
        if (more) { WAITV(8); } else { WAITV(4); }
        BARRIER();
        if (more) STAGE2(xbn1, 1, 1 * XBUF);
        COMPUTE_FOLD(2, 2 * XBUF);

        // p3: stage (n+1,q2)->buf2, then compute buf3; combine + store
        if (more) { WAITV(8); } else { WAITV(0); }
        BARRIER();
        if (more) STAGE2(xbn1, 2, 2 * XBUF);
        COMPUTE_FOLD(3, 3 * XBUF);
#pragma unroll
        for (int nn = 0; nn < 2; ++nn) {
#pragma unroll
            for (int r = 0; r < 4; ++r) {
                reS[nn][r] += __shfl_xor(reS[nn][r], 1);
                reS[nn][r] += __shfl_xor(reS[nn][r], 2);
                reS[nn][r] += __shfl_xor(reS[nn][r], 4);
                reS[nn][r] += __shfl_xor(reS[nn][r], 8);
            }
        }
        if (jh == 0 && li == 0) {
#pragma unroll
            for (int nn = 0; nn < 2; ++nn) {
                f32x4 o;
                o[0] = reS[nn][0]; o[1] = reS[nn][1];
                o[2] = reS[nn][2]; o[3] = reS[nn][3];
                *(f32x4*)(part + (iw * 2 + nn) * 16 + s * 4) = o;
            }
        }
        WAITLGKM();
        BARRIER();                       // part visible to jh1
        if (jh == 1 && li == 0) {
#pragma unroll
            for (int nn = 0; nn < 2; ++nn) {
                f32x4 pv = *(const f32x4*)(part + (iw * 2 + nn) * 16 + s * 4);
                int oi = (bat0 + n) * EDIM + (iw * 2 + nn) * 16 + s * 4;
                if (oi + 3 < nout) {
                    f32x4 o;
                    o[0] = reS[nn][0] + pv[0];
                    o[1] = reS[nn][1] + pv[1];
                    o[2] = reS[nn][2] + pv[2];
                    o[3] = reS[nn][3] + pv[3];
                    *(f32x4*)(out + oi) = o;
                }
            }
        }
        reS[0][0]=reS[0][1]=reS[0][2]=reS[0][3]=0.f;
        reS[1][0]=reS[1][1]=reS[1][2]=reS[1][3]=0.f;
    }
}

extern "C" void kernel_launch(void* const* d_in, const int* in_sizes, int n_in,
                              void* d_out, int out_size, void* d_ws, size_t ws_size,
                              hipStream_t stream) {
    const float* R    = (const float*)d_in[0];
    const float* M    = (const float*)d_in[1];
    const float* Kern = (const float*)d_in[2];
    float*       out  = (float*)d_out;
    const int    B    = in_sizes[0] / (EDIM * EDIM);   // 2048

    hipFuncSetAttribute((const void*)qmeas_kernel,
                        hipFuncAttributeMaxDynamicSharedMemorySize, LDS_BYTES);

    int grid = B / NBAT;   // 256
    qmeas_kernel<<<grid, 512, LDS_BYTES, stream>>>(R, M, Kern, out, out_size);
}